// Round 11
// baseline (264.278 us; speedup 1.0000x reference)
//
#include <hip/hip_runtime.h>
#include <hip/hip_bf16.h>
#include <math.h>

#define N_NODES 50000
#define N_EDGES 1600000
#define CH 128
#define NF 50
#define NR 8192            // ef(r) nearest table resolution (bf16, 2 MB)
#define NB 1563            // buckets of 32 nodes (ceil(50000/32))
#define BUCKET_NODES 32    // power of 2 -> bucket id is a shift
#define CAP 1280           // bucket capacity: mean 1024, sd 32 -> +8 sigma; 1280 = 5*256
#define PASSA_CHUNK 4096   // edges per scatter block (R2-measured 81us config)
#define NBLK_SCAT 391      // ceil(E / PASSA_CHUNK)
#define NBLK_TB   128      // NR/64
#define NBLK_DH   782      // ceil(N/64)

constexpr float DELTA  = 5.0f / 49.0f;
constexpr float COEF   = 1.0f / (2.0f * DELTA * DELTA);
constexpr float LOG2_  = 0.6931471805599453f;
constexpr float RSCALE = (float)(NR - 1) / 5.0f;

typedef short  bf16x8 __attribute__((ext_vector_type(8)));
typedef float  f32x4  __attribute__((ext_vector_type(4)));
typedef unsigned short ushort_t;
typedef unsigned long long u64;

__device__ __forceinline__ float ssp(float x) {
    return fmaxf(x, 0.0f) + __logf(1.0f + __expf(-fabsf(x))) - LOG2_;
}
__device__ __forceinline__ ushort_t f2bf(float x) {
    __hip_bfloat16 b = __float2bfloat16(x);
    return *reinterpret_cast<ushort_t*>(&b);
}
__device__ __forceinline__ float bf2f(ushort_t u) {
    return __uint_as_float(((unsigned)u) << 16);
}
__device__ __forceinline__ float4 f4zero() { return make_float4(0.f, 0.f, 0.f, 0.f); }

// ---------------------------------------------------------------------------
// K1: weight prep (blocks 0..63) + zero bcnt (block 64).
// ---------------------------------------------------------------------------
__global__ __launch_bounds__(256) void k1_prep(const float* __restrict__ Wlin,
                                               const float* __restrict__ Wm1,
                                               const float* __restrict__ Wm2,
                                               const float* __restrict__ Wf1,
                                               const float* __restrict__ Wf2,
                                               ushort_t* __restrict__ wlhi,
                                               ushort_t* __restrict__ wllo,
                                               ushort_t* __restrict__ wm1hi,
                                               ushort_t* __restrict__ wm1lo,
                                               ushort_t* __restrict__ wm2hi,
                                               ushort_t* __restrict__ wm2lo,
                                               ushort_t* __restrict__ wf1t,
                                               ushort_t* __restrict__ wf2hi,
                                               ushort_t* __restrict__ wf2lo,
                                               int* __restrict__ bcnt) {
    const int tid = threadIdx.x;
    if (blockIdx.x == 64) {
        for (int i = tid; i < NB; i += 256) bcnt[i] = 0;
        return;
    }
    int idx = blockIdx.x * 256 + tid;   // 0..16383
    int n = idx >> 7, k = idx & 127;
    {   float w = Wlin[(size_t)n * CH + k];
        ushort_t hi = f2bf(w); wlhi[n * CH + k] = hi; wllo[n * CH + k] = f2bf(w - bf2f(hi)); }
    {   float w = Wm1[(size_t)k * CH + n];
        ushort_t hi = f2bf(w); wm1hi[n * CH + k] = hi; wm1lo[n * CH + k] = f2bf(w - bf2f(hi)); }
    {   float w = Wm2[(size_t)k * CH + n];
        ushort_t hi = f2bf(w); wm2hi[n * CH + k] = hi; wm2lo[n * CH + k] = f2bf(w - bf2f(hi)); }
    if (k < 64) wf1t[n * 64 + k] = (k < NF) ? f2bf(Wf1[k * CH + n]) : (ushort_t)0;
    {   float w = Wf2[(size_t)k * CH + n];
        ushort_t hi = f2bf(w); wf2hi[n * CH + k] = hi; wf2lo[n * CH + k] = f2bf(w - bf2f(hi)); }
}

// ---------------------------------------------------------------------------
// K2 bodies
// ---------------------------------------------------------------------------
// Bucketed two-pass scatter (R2-measured form: 4096-edge chunks, 391 blocks).
__device__ void scatter_body(char* smem, int blk,
                             const int* __restrict__ recv,
                             const int* __restrict__ send,
                             const float* __restrict__ dist,
                             int* __restrict__ bcnt,
                             u64* __restrict__ brec) {
    int* bcur   = (int*)smem;          // [NB] 6.3 KB
    int* bbaseL = bcur + NB;           // [NB] 6.3 KB
    const int tid = threadIdx.x;
    for (int i = tid; i < NB; i += 256) bcur[i] = 0;
    __syncthreads();
    const int e0 = blk * PASSA_CHUNK;
#pragma unroll
    for (int i = 0; i < 16; i++) {
        int e = e0 + tid + i * 256;
        if (e < N_EDGES) atomicAdd(&bcur[recv[e] / BUCKET_NODES], 1);
    }
    __syncthreads();
    for (int i = tid; i < NB; i += 256) {
        int c = bcur[i];
        bbaseL[i] = c ? atomicAdd(&bcnt[i], c) : 0;
        bcur[i] = 0;
    }
    __syncthreads();
#pragma unroll
    for (int i = 0; i < 16; i++) {
        int e = e0 + tid + i * 256;
        if (e < N_EDGES) {
            int r = recv[e];
            int b = r / BUCKET_NODES;
            int rank = bbaseL[b] + atomicAdd(&bcur[b], 1);
            if (rank < CAP) {
                float x = fminf(dist[e] * RSCALE, (float)(NR - 1));
                int ti = __float2int_rn(x);
                u64 rec = (u64)(unsigned)(send[e] | (r << 16)) | ((u64)ti << 32);
                brec[(size_t)b * CAP + rank] = rec;
            }
        }
    }
}

// MFMA ef-table build: 64 grid points per block.
__device__ void table_body(char* smem, int blk,
                           const float* __restrict__ bf1,
                           const float* __restrict__ bf2,
                           const ushort_t* __restrict__ wf1t,
                           const ushort_t* __restrict__ wf2hi,
                           const ushort_t* __restrict__ wf2lo,
                           ushort_t* __restrict__ tabn) {
    ushort_t (*basis)[72] = (ushort_t (*)[72])smem;                 // 9216 B
    ushort_t (*t1s)[136]  = (ushort_t (*)[136])(smem + 64 * 72 * 2);// 17408 B
    const int tid = threadIdx.x;
    const int g0  = blk * 64;

    for (int i = tid; i < 64 * 64; i += 256) {
        int e = i >> 6, k = i & 63;
        float val = 0.f;
        if (k < NF) {
            float r = (float)(g0 + e) * (5.0f / (float)(NR - 1));
            float d = r - (float)k * DELTA;
            val = __expf(-COEF * d * d);
        }
        basis[e][k] = f2bf(val);
    }
    __syncthreads();

    const int lane = tid & 63;
    const int wv   = tid >> 6;
    const int row  = lane & 15;
    const int quad = lane >> 4;
    const int c0   = (2 * wv) * 16 + row;
    const int c1   = c0 + 16;

    f32x4 acc[2][4];
#pragma unroll
    for (int j = 0; j < 2; j++)
#pragma unroll
        for (int rt = 0; rt < 4; rt++) acc[j][rt] = (f32x4){0.f, 0.f, 0.f, 0.f};

#pragma unroll
    for (int kb = 0; kb < 64; kb += 32) {
        bf16x8 B0 = *(const bf16x8*)&wf1t[c0 * 64 + kb + quad * 8];
        bf16x8 B1 = *(const bf16x8*)&wf1t[c1 * 64 + kb + quad * 8];
#pragma unroll
        for (int rt = 0; rt < 4; rt++) {
            bf16x8 A = *(const bf16x8*)&basis[rt * 16 + row][kb + quad * 8];
            acc[0][rt] = __builtin_amdgcn_mfma_f32_16x16x32_bf16(A, B0, acc[0][rt], 0, 0, 0);
            acc[1][rt] = __builtin_amdgcn_mfma_f32_16x16x32_bf16(A, B1, acc[1][rt], 0, 0, 0);
        }
    }
    {
        float b1v[2] = { bf1[c0], bf1[c1] };
#pragma unroll
        for (int j = 0; j < 2; j++) {
            int c = j ? c1 : c0;
#pragma unroll
            for (int rt = 0; rt < 4; rt++)
#pragma unroll
                for (int rg = 0; rg < 4; rg++) {
                    int e = rt * 16 + quad * 4 + rg;
                    t1s[e][c] = f2bf(ssp(acc[j][rt][rg] + b1v[j]));
                }
        }
    }
    __syncthreads();

#pragma unroll
    for (int j = 0; j < 2; j++)
#pragma unroll
        for (int rt = 0; rt < 4; rt++) acc[j][rt] = (f32x4){0.f, 0.f, 0.f, 0.f};

#pragma unroll
    for (int kb = 0; kb < 128; kb += 32) {
        bf16x8 B0h = *(const bf16x8*)&wf2hi[c0 * CH + kb + quad * 8];
        bf16x8 B0l = *(const bf16x8*)&wf2lo[c0 * CH + kb + quad * 8];
        bf16x8 B1h = *(const bf16x8*)&wf2hi[c1 * CH + kb + quad * 8];
        bf16x8 B1l = *(const bf16x8*)&wf2lo[c1 * CH + kb + quad * 8];
#pragma unroll
        for (int rt = 0; rt < 4; rt++) {
            bf16x8 A = *(const bf16x8*)&t1s[rt * 16 + row][kb + quad * 8];
            acc[0][rt] = __builtin_amdgcn_mfma_f32_16x16x32_bf16(A, B0l, acc[0][rt], 0, 0, 0);
            acc[0][rt] = __builtin_amdgcn_mfma_f32_16x16x32_bf16(A, B0h, acc[0][rt], 0, 0, 0);
            acc[1][rt] = __builtin_amdgcn_mfma_f32_16x16x32_bf16(A, B1l, acc[1][rt], 0, 0, 0);
            acc[1][rt] = __builtin_amdgcn_mfma_f32_16x16x32_bf16(A, B1h, acc[1][rt], 0, 0, 0);
        }
    }
    {
        float b2v[2] = { bf2[c0], bf2[c1] };
#pragma unroll
        for (int j = 0; j < 2; j++) {
            int c = j ? c1 : c0;
#pragma unroll
            for (int rt = 0; rt < 4; rt++)
#pragma unroll
                for (int rg = 0; rg < 4; rg++) {
                    int g = g0 + rt * 16 + quad * 4 + rg;
                    tabn[(size_t)g * CH + c] = f2bf(acc[j][rt][rg] + b2v[j]);
                }
        }
    }
}

__device__ void dense_h_body(char* smem, int blk,
                             const float* __restrict__ X,
                             const ushort_t* __restrict__ Bhi,
                             const ushort_t* __restrict__ Blo,
                             ushort_t* __restrict__ Y) {
    ushort_t (*xs)[136] = (ushort_t (*)[136])smem;
    const int tid  = threadIdx.x;
    const int row0 = blk * 64;

#pragma unroll
    for (int i = 0; i < 8; i++) {
        int idx = tid + i * 256;
        int r   = idx >> 5;
        int c4  = (idx & 31) * 4;
        float4 v = (row0 + r < N_NODES) ? *(const float4*)&X[(size_t)(row0 + r) * CH + c4]
                                        : f4zero();
        ushort4 s;
        s.x = f2bf(v.x); s.y = f2bf(v.y); s.z = f2bf(v.z); s.w = f2bf(v.w);
        *(ushort4*)&xs[r][c4] = s;
    }
    __syncthreads();

    const int lane = tid & 63;
    const int wv   = tid >> 6;
    const int row  = lane & 15;
    const int quad = lane >> 4;
    const int c0   = (2 * wv) * 16 + row;
    const int c1   = c0 + 16;

    f32x4 acc[2][4];
#pragma unroll
    for (int j = 0; j < 2; j++)
#pragma unroll
        for (int rt = 0; rt < 4; rt++) acc[j][rt] = (f32x4){0.f, 0.f, 0.f, 0.f};

#pragma unroll
    for (int kb = 0; kb < 128; kb += 32) {
        bf16x8 B0h = *(const bf16x8*)&Bhi[(size_t)c0 * CH + kb + quad * 8];
        bf16x8 B0l = *(const bf16x8*)&Blo[(size_t)c0 * CH + kb + quad * 8];
        bf16x8 B1h = *(const bf16x8*)&Bhi[(size_t)c1 * CH + kb + quad * 8];
        bf16x8 B1l = *(const bf16x8*)&Blo[(size_t)c1 * CH + kb + quad * 8];
#pragma unroll
        for (int rt = 0; rt < 4; rt++) {
            bf16x8 A = *(const bf16x8*)&xs[rt * 16 + row][kb + quad * 8];
            acc[0][rt] = __builtin_amdgcn_mfma_f32_16x16x32_bf16(A, B0l, acc[0][rt], 0, 0, 0);
            acc[0][rt] = __builtin_amdgcn_mfma_f32_16x16x32_bf16(A, B0h, acc[0][rt], 0, 0, 0);
            acc[1][rt] = __builtin_amdgcn_mfma_f32_16x16x32_bf16(A, B1l, acc[1][rt], 0, 0, 0);
            acc[1][rt] = __builtin_amdgcn_mfma_f32_16x16x32_bf16(A, B1h, acc[1][rt], 0, 0, 0);
        }
    }

#pragma unroll
    for (int j = 0; j < 2; j++) {
        int c = j ? c1 : c0;
#pragma unroll
        for (int rt = 0; rt < 4; rt++)
#pragma unroll
            for (int rg = 0; rg < 4; rg++) {
                int r = row0 + rt * 16 + quad * 4 + rg;
                if (r < N_NODES) Y[(size_t)r * CH + c] = f2bf(acc[j][rt][rg]);
            }
    }
}

__global__ __launch_bounds__(256) void k2_mega(const int* __restrict__ recv,
                                               const int* __restrict__ send,
                                               const float* __restrict__ dist,
                                               int* __restrict__ bcnt,
                                               u64* __restrict__ brec,
                                               const float* __restrict__ bf1,
                                               const float* __restrict__ bf2,
                                               const ushort_t* __restrict__ wf1t,
                                               const ushort_t* __restrict__ wf2hi,
                                               const ushort_t* __restrict__ wf2lo,
                                               ushort_t* __restrict__ tabn,
                                               const float* __restrict__ X,
                                               const ushort_t* __restrict__ wlhi,
                                               const ushort_t* __restrict__ wllo,
                                               ushort_t* __restrict__ h) {
    __shared__ __align__(16) char smem[64 * 72 * 2 + 64 * 136 * 2];   // 26624 B
    const int blk = blockIdx.x;
    if (blk < NBLK_SCAT) {
        scatter_body(smem, blk, recv, send, dist, bcnt, brec);
    } else if (blk < NBLK_SCAT + NBLK_TB) {
        table_body(smem, blk - NBLK_SCAT, bf1, bf2, wf1t, wf2hi, wf2lo, tabn);
    } else {
        dense_h_body(smem, blk - NBLK_SCAT - NBLK_TB, X, wlhi, wllo, h);
    }
}

// ---------------------------------------------------------------------------
// K3: fused sort + gather + output MLP.
// Single-pass sort (regs cache 5 recs). EDGE-BALANCED gather: group g takes
// contiguous 1/16 of the sorted edge array (perfect balance), accumulates in
// regs while node unchanged, flushes partials via LDS f32 atomicAdd into an
// f32 tile. MLP GEMM1 converts f32->bf16 inline on A-reads; ts aliases atf.
// ---------------------------------------------------------------------------
__global__ __launch_bounds__(256) void sort_gather_mlp(const int* __restrict__ bcnt,
                                                       const u64* __restrict__ brec,
                                                       const ushort_t* __restrict__ h,
                                                       const ushort_t* __restrict__ tabn,
                                                       const ushort_t* __restrict__ B1hi,
                                                       const ushort_t* __restrict__ B1lo,
                                                       const float* __restrict__ bm1,
                                                       const ushort_t* __restrict__ B2hi,
                                                       const ushort_t* __restrict__ B2lo,
                                                       const float* __restrict__ bm2,
                                                       float* __restrict__ OUT) {
    __shared__ int shist[BUCKET_NODES];
    __shared__ int sbeg[BUCKET_NODES];
    __shared__ int sexc[BUCKET_NODES];
    __shared__ unsigned sout[CAP];                     // 5120 B
    __shared__ __align__(16) float atf[32][132];       // 16896 B; ts aliases front
    const int b = blockIdx.x, tid = threadIdx.x;
    const int nbase = b * BUCKET_NODES;
    const int nn = min(BUCKET_NODES, N_NODES - nbase);
    if (nn <= 0) return;
    const int m = min(bcnt[b], CAP);
    const u64* my = brec + (size_t)b * CAP;

    if (tid < BUCKET_NODES) shist[tid] = 0;
    // zero the f32 acc tile (32*132 floats = 1056 float4, incl. pad - harmless)
    for (int i = tid; i < 1056; i += 256) ((float4*)atf)[i] = f4zero();
    __syncthreads();

    // Single pass: load recs into registers + histogram.
    unsigned pw0 = 0, pw1 = 0, pw2 = 0, pw3 = 0, pw4 = 0;
    int lc0 = -1, lc1 = -1, lc2 = -1, lc3 = -1, lc4 = -1;
    {
        int i;
        i = tid;           if (i < m) { u64 rec = my[i]; lc0 = (int)((rec >> 16) & 0xFFFF) - nbase; pw0 = (unsigned)(rec & 0xFFFF) | ((unsigned)((rec >> 32) & 0x3FFF) << 16); }
        i = tid + 256;     if (i < m) { u64 rec = my[i]; lc1 = (int)((rec >> 16) & 0xFFFF) - nbase; pw1 = (unsigned)(rec & 0xFFFF) | ((unsigned)((rec >> 32) & 0x3FFF) << 16); }
        i = tid + 512;     if (i < m) { u64 rec = my[i]; lc2 = (int)((rec >> 16) & 0xFFFF) - nbase; pw2 = (unsigned)(rec & 0xFFFF) | ((unsigned)((rec >> 32) & 0x3FFF) << 16); }
        i = tid + 768;     if (i < m) { u64 rec = my[i]; lc3 = (int)((rec >> 16) & 0xFFFF) - nbase; pw3 = (unsigned)(rec & 0xFFFF) | ((unsigned)((rec >> 32) & 0x3FFF) << 16); }
        i = tid + 1024;    if (i < m) { u64 rec = my[i]; lc4 = (int)((rec >> 16) & 0xFFFF) - nbase; pw4 = (unsigned)(rec & 0xFFFF) | ((unsigned)((rec >> 32) & 0x3FFF) << 16); }
        if (lc0 >= 0) atomicAdd(&shist[lc0], 1);
        if (lc1 >= 0) atomicAdd(&shist[lc1], 1);
        if (lc2 >= 0) atomicAdd(&shist[lc2], 1);
        if (lc3 >= 0) atomicAdd(&shist[lc3], 1);
        if (lc4 >= 0) atomicAdd(&shist[lc4], 1);
    }
    __syncthreads();
    if (tid == 0) {
        int acc = 0;
#pragma unroll
        for (int l = 0; l < BUCKET_NODES; l++) {
            sexc[l] = acc; sbeg[l] = acc; acc += shist[l];
        }
    }
    __syncthreads();
    {
        if (lc0 >= 0) { int rank = atomicAdd(&sexc[lc0], 1); sout[rank] = pw0; }
        if (lc1 >= 0) { int rank = atomicAdd(&sexc[lc1], 1); sout[rank] = pw1; }
        if (lc2 >= 0) { int rank = atomicAdd(&sexc[lc2], 1); sout[rank] = pw2; }
        if (lc3 >= 0) { int rank = atomicAdd(&sexc[lc3], 1); sout[rank] = pw3; }
        if (lc4 >= 0) { int rank = atomicAdd(&sexc[lc4], 1); sout[rank] = pw4; }
    }
    __syncthreads();

    // Phase 2: EDGE-BALANCED gather. Group g (16 lanes, 8 ch each) processes
    // edges [g*per, min(m,(g+1)*per)); reg-accumulate per node, LDS-atomic flush.
    {
        const int g   = tid >> 4;
        const int c8  = (tid & 15) * 8;
        const int per = (m + 15) >> 4;
        const int e0g = g * per;
        const int e1g = min(m, e0g + per);

        float acc[8];
#pragma unroll
        for (int j = 0; j < 8; j++) acc[j] = 0.f;
        int l = 0;
        while (l < nn && sbeg[l] + shist[l] <= e0g) l++;

        int e = e0g;
        for (; e + 8 <= e1g; e += 8) {
            unsigned v[8];
#pragma unroll
            for (int u = 0; u < 8; u++) v[u] = sout[e + u];
            bf16x8 hu[8], tn[8];
#pragma unroll
            for (int u = 0; u < 8; u++) {
                int s  = (int)(v[u] & 0xFFFF);
                int ti = (int)(v[u] >> 16);
                hu[u] = *(const bf16x8*)&h[(size_t)s * CH + c8];
                tn[u] = *(const bf16x8*)&tabn[(size_t)ti * CH + c8];
            }
#pragma unroll
            for (int u = 0; u < 8; u++) {
                int ee = e + u;
                while (ee >= sbeg[l] + shist[l]) {
#pragma unroll
                    for (int j = 0; j < 8; j++) { atomicAdd(&atf[l][c8 + j], acc[j]); acc[j] = 0.f; }
                    l++;
                }
#pragma unroll
                for (int j = 0; j < 8; j++)
                    acc[j] = fmaf(bf2f((ushort_t)hu[u][j]), bf2f((ushort_t)tn[u][j]), acc[j]);
            }
        }
        for (; e < e1g; e++) {
            unsigned v = sout[e];
            while (e >= sbeg[l] + shist[l]) {
#pragma unroll
                for (int j = 0; j < 8; j++) { atomicAdd(&atf[l][c8 + j], acc[j]); acc[j] = 0.f; }
                l++;
            }
            int s  = (int)(v & 0xFFFF);
            int ti = (int)(v >> 16);
            bf16x8 hu = *(const bf16x8*)&h[(size_t)s * CH + c8];
            bf16x8 tn = *(const bf16x8*)&tabn[(size_t)ti * CH + c8];
#pragma unroll
            for (int j = 0; j < 8; j++)
                acc[j] = fmaf(bf2f((ushort_t)hu[j]), bf2f((ushort_t)tn[j]), acc[j]);
        }
        if (e1g > e0g && l < nn) {
#pragma unroll
            for (int j = 0; j < 8; j++) atomicAdd(&atf[l][c8 + j], acc[j]);
        }
    }
    __syncthreads();

    // Phase 3: 32-row 2-layer MFMA MLP. GEMM1 A-reads convert f32->bf16 inline.
    const int lane = tid & 63;
    const int wv   = tid >> 6;
    const int row  = lane & 15;
    const int quad = lane >> 4;
    const int c0   = (2 * wv) * 16 + row;
    const int c1   = c0 + 16;

    f32x4 acc[2][2];
#pragma unroll
    for (int j = 0; j < 2; j++)
#pragma unroll
        for (int rt = 0; rt < 2; rt++) acc[j][rt] = (f32x4){0.f, 0.f, 0.f, 0.f};

#pragma unroll
    for (int kb = 0; kb < 128; kb += 32) {
        bf16x8 B0h = *(const bf16x8*)&B1hi[(size_t)c0 * CH + kb + quad * 8];
        bf16x8 B0l = *(const bf16x8*)&B1lo[(size_t)c0 * CH + kb + quad * 8];
        bf16x8 B1h_ = *(const bf16x8*)&B1hi[(size_t)c1 * CH + kb + quad * 8];
        bf16x8 B1l_ = *(const bf16x8*)&B1lo[(size_t)c1 * CH + kb + quad * 8];
#pragma unroll
        for (int rt = 0; rt < 2; rt++) {
            const float* ap = &atf[rt * 16 + row][kb + quad * 8];
            bf16x8 A;
#pragma unroll
            for (int j = 0; j < 8; j++) A[j] = (short)f2bf(ap[j]);
            acc[0][rt] = __builtin_amdgcn_mfma_f32_16x16x32_bf16(A, B0l, acc[0][rt], 0, 0, 0);
            acc[0][rt] = __builtin_amdgcn_mfma_f32_16x16x32_bf16(A, B0h, acc[0][rt], 0, 0, 0);
            acc[1][rt] = __builtin_amdgcn_mfma_f32_16x16x32_bf16(A, B1l_, acc[1][rt], 0, 0, 0);
            acc[1][rt] = __builtin_amdgcn_mfma_f32_16x16x32_bf16(A, B1h_, acc[1][rt], 0, 0, 0);
        }
    }
    __syncthreads();   // GEMM1 reads of atf complete before ts overwrite
    ushort_t (*ts)[136] = (ushort_t (*)[136])atf;      // 8704 B alias
    {
        float bv[2] = { bm1[c0], bm1[c1] };
#pragma unroll
        for (int j = 0; j < 2; j++) {
            int c = j ? c1 : c0;
#pragma unroll
            for (int rt = 0; rt < 2; rt++)
#pragma unroll
                for (int rg = 0; rg < 4; rg++)
                    ts[rt * 16 + quad * 4 + rg][c] = f2bf(ssp(acc[j][rt][rg] + bv[j]));
        }
    }
    __syncthreads();

#pragma unroll
    for (int j = 0; j < 2; j++)
#pragma unroll
        for (int rt = 0; rt < 2; rt++) acc[j][rt] = (f32x4){0.f, 0.f, 0.f, 0.f};

#pragma unroll
    for (int kb = 0; kb < 128; kb += 32) {
        bf16x8 B0h = *(const bf16x8*)&B2hi[(size_t)c0 * CH + kb + quad * 8];
        bf16x8 B0l = *(const bf16x8*)&B2lo[(size_t)c0 * CH + kb + quad * 8];
        bf16x8 B1h_ = *(const bf16x8*)&B2hi[(size_t)c1 * CH + kb + quad * 8];
        bf16x8 B1l_ = *(const bf16x8*)&B2lo[(size_t)c1 * CH + kb + quad * 8];
#pragma unroll
        for (int rt = 0; rt < 2; rt++) {
            bf16x8 A = *(const bf16x8*)&ts[rt * 16 + row][kb + quad * 8];
            acc[0][rt] = __builtin_amdgcn_mfma_f32_16x16x32_bf16(A, B0l, acc[0][rt], 0, 0, 0);
            acc[0][rt] = __builtin_amdgcn_mfma_f32_16x16x32_bf16(A, B0h, acc[0][rt], 0, 0, 0);
            acc[1][rt] = __builtin_amdgcn_mfma_f32_16x16x32_bf16(A, B1l_, acc[1][rt], 0, 0, 0);
            acc[1][rt] = __builtin_amdgcn_mfma_f32_16x16x32_bf16(A, B1h_, acc[1][rt], 0, 0, 0);
        }
    }
    {
        float bv[2] = { bm2[c0], bm2[c1] };
#pragma unroll
        for (int j = 0; j < 2; j++) {
            int c = j ? c1 : c0;
#pragma unroll
            for (int rt = 0; rt < 2; rt++)
#pragma unroll
                for (int rg = 0; rg < 4; rg++) {
                    int r = rt * 16 + quad * 4 + rg;
                    if (r < nn) OUT[(size_t)(nbase + r) * CH + c] = acc[j][rt][rg] + bv[j];
                }
        }
    }
}

// ---------------------------------------------------------------------------
extern "C" void kernel_launch(void* const* d_in, const int* in_sizes, int n_in,
                              void* d_out, int out_size, void* d_ws, size_t ws_size,
                              hipStream_t stream) {
    const float* features = (const float*)d_in[0];
    const float* dist     = (const float*)d_in[1];
    const float* W_lin    = (const float*)d_in[2];
    const float* Wf1      = (const float*)d_in[3];
    const float* bf1      = (const float*)d_in[4];
    const float* Wf2      = (const float*)d_in[5];
    const float* bf2      = (const float*)d_in[6];
    const float* Wm1      = (const float*)d_in[7];
    const float* bm1      = (const float*)d_in[8];
    const float* Wm2      = (const float*)d_in[9];
    const float* bm2      = (const float*)d_in[10];
    const int* senders    = (const int*)d_in[11];
    const int* receivers  = (const int*)d_in[12];
    float* out = (float*)d_out;

    // workspace (~31 MB)
    u64* brec       = (u64*)d_ws;                            // [NB*CAP] 16.0 MB
    ushort_t* h     = (ushort_t*)(brec + (size_t)NB * CAP);  // [N,128] 12.8 MB
    ushort_t* tabn  = h + (size_t)N_NODES * CH;              // [NR,128] 2 MB
    int* bcnt       = (int*)(tabn + (size_t)NR * CH);        // [NB] 6.3 KB
    ushort_t* wlhi  = (ushort_t*)(bcnt + NB);
    ushort_t* wllo  = wlhi  + CH * CH;
    ushort_t* wm1hi = wllo  + CH * CH;
    ushort_t* wm1lo = wm1hi + CH * CH;
    ushort_t* wm2hi = wm1lo + CH * CH;
    ushort_t* wm2lo = wm2hi + CH * CH;
    ushort_t* wf1t  = wm2lo + CH * CH;                       // [128*64]
    ushort_t* wf2hi = wf1t  + CH * 64;
    ushort_t* wf2lo = wf2hi + CH * CH;

    // K1: weight prep + zero bcnt
    k1_prep<<<65, 256, 0, stream>>>(W_lin, Wm1, Wm2, Wf1, Wf2,
                                    wlhi, wllo, wm1hi, wm1lo, wm2hi, wm2lo,
                                    wf1t, wf2hi, wf2lo, bcnt);

    // K2: [bucket_scatter | table_mfma | dense_h]
    k2_mega<<<NBLK_SCAT + NBLK_TB + NBLK_DH, 256, 0, stream>>>(
        receivers, senders, dist, bcnt, brec,
        bf1, bf2, wf1t, wf2hi, wf2lo, tabn,
        features, wlhi, wllo, h);

    // K3: fused sort + gather + output MLP -> d_out (1563 blocks)
    sort_gather_mlp<<<NB, 256, 0, stream>>>(bcnt, brec, h, tabn,
                                            wm1hi, wm1lo, bm1,
                                            wm2hi, wm2lo, bm2, out);
}

// Round 12
// 249.330 us; speedup vs baseline: 1.0599x; 1.0599x over previous
//
#include <hip/hip_runtime.h>
#include <hip/hip_bf16.h>
#include <math.h>

#define N_NODES 50000
#define N_EDGES 1600000
#define CH 128
#define NF 50
#define NR 8192            // ef(r) nearest table resolution (bf16, 2 MB)
#define NB 1563            // buckets of 32 nodes (ceil(50000/32))
#define BUCKET_NODES 32    // power of 2 -> bucket id is a shift
#define CAP 1280           // bucket capacity: mean 1024, sd 32 -> +8 sigma; 1280 = 5*256
#define PASSA_CHUNK 4096   // edges per scatter block (R2-measured config)
#define NBLK_SCAT 391      // ceil(E / PASSA_CHUNK)
#define NBLK_TB   128      // NR/64
#define NBLK_DH   782      // ceil(N/64)

constexpr float DELTA  = 5.0f / 49.0f;
constexpr float COEF   = 1.0f / (2.0f * DELTA * DELTA);
constexpr float LOG2_  = 0.6931471805599453f;
constexpr float RSCALE = (float)(NR - 1) / 5.0f;

typedef short  bf16x8 __attribute__((ext_vector_type(8)));
typedef float  f32x4  __attribute__((ext_vector_type(4)));
typedef unsigned short ushort_t;
typedef unsigned long long u64;

__device__ __forceinline__ float ssp(float x) {
    return fmaxf(x, 0.0f) + __logf(1.0f + __expf(-fabsf(x))) - LOG2_;
}
__device__ __forceinline__ ushort_t f2bf(float x) {
    __hip_bfloat16 b = __float2bfloat16(x);
    return *reinterpret_cast<ushort_t*>(&b);
}
__device__ __forceinline__ float bf2f(ushort_t u) {
    return __uint_as_float(((unsigned)u) << 16);
}
__device__ __forceinline__ float4 f4zero() { return make_float4(0.f, 0.f, 0.f, 0.f); }

// ---------------------------------------------------------------------------
// K1: weight prep (blocks 0..63) + zero bcnt (block 64).
// ---------------------------------------------------------------------------
__global__ __launch_bounds__(256) void k1_prep(const float* __restrict__ Wlin,
                                               const float* __restrict__ Wm1,
                                               const float* __restrict__ Wm2,
                                               const float* __restrict__ Wf1,
                                               const float* __restrict__ Wf2,
                                               ushort_t* __restrict__ wlhi,
                                               ushort_t* __restrict__ wllo,
                                               ushort_t* __restrict__ wm1hi,
                                               ushort_t* __restrict__ wm1lo,
                                               ushort_t* __restrict__ wm2hi,
                                               ushort_t* __restrict__ wm2lo,
                                               ushort_t* __restrict__ wf1t,
                                               ushort_t* __restrict__ wf2hi,
                                               ushort_t* __restrict__ wf2lo,
                                               int* __restrict__ bcnt) {
    const int tid = threadIdx.x;
    if (blockIdx.x == 64) {
        for (int i = tid; i < NB; i += 256) bcnt[i] = 0;
        return;
    }
    int idx = blockIdx.x * 256 + tid;   // 0..16383
    int n = idx >> 7, k = idx & 127;
    {   float w = Wlin[(size_t)n * CH + k];
        ushort_t hi = f2bf(w); wlhi[n * CH + k] = hi; wllo[n * CH + k] = f2bf(w - bf2f(hi)); }
    {   float w = Wm1[(size_t)k * CH + n];
        ushort_t hi = f2bf(w); wm1hi[n * CH + k] = hi; wm1lo[n * CH + k] = f2bf(w - bf2f(hi)); }
    {   float w = Wm2[(size_t)k * CH + n];
        ushort_t hi = f2bf(w); wm2hi[n * CH + k] = hi; wm2lo[n * CH + k] = f2bf(w - bf2f(hi)); }
    if (k < 64) wf1t[n * 64 + k] = (k < NF) ? f2bf(Wf1[k * CH + n]) : (ushort_t)0;
    {   float w = Wf2[(size_t)k * CH + n];
        ushort_t hi = f2bf(w); wf2hi[n * CH + k] = hi; wf2lo[n * CH + k] = f2bf(w - bf2f(hi)); }
}

// ---------------------------------------------------------------------------
// K2 bodies
// ---------------------------------------------------------------------------
// Bucketed two-pass scatter (R2-measured form: 4096-edge chunks, 391 blocks).
__device__ void scatter_body(char* smem, int blk,
                             const int* __restrict__ recv,
                             const int* __restrict__ send,
                             const float* __restrict__ dist,
                             int* __restrict__ bcnt,
                             u64* __restrict__ brec) {
    int* bcur   = (int*)smem;          // [NB] 6.3 KB
    int* bbaseL = bcur + NB;           // [NB] 6.3 KB
    const int tid = threadIdx.x;
    for (int i = tid; i < NB; i += 256) bcur[i] = 0;
    __syncthreads();
    const int e0 = blk * PASSA_CHUNK;
#pragma unroll
    for (int i = 0; i < 16; i++) {
        int e = e0 + tid + i * 256;
        if (e < N_EDGES) atomicAdd(&bcur[recv[e] / BUCKET_NODES], 1);
    }
    __syncthreads();
    for (int i = tid; i < NB; i += 256) {
        int c = bcur[i];
        bbaseL[i] = c ? atomicAdd(&bcnt[i], c) : 0;
        bcur[i] = 0;
    }
    __syncthreads();
#pragma unroll
    for (int i = 0; i < 16; i++) {
        int e = e0 + tid + i * 256;
        if (e < N_EDGES) {
            int r = recv[e];
            int b = r / BUCKET_NODES;
            int rank = bbaseL[b] + atomicAdd(&bcur[b], 1);
            if (rank < CAP) {
                float x = fminf(dist[e] * RSCALE, (float)(NR - 1));
                int ti = __float2int_rn(x);
                u64 rec = (u64)(unsigned)(send[e] | (r << 16)) | ((u64)ti << 32);
                brec[(size_t)b * CAP + rank] = rec;
            }
        }
    }
}

// MFMA ef-table build: 64 grid points per block.
__device__ void table_body(char* smem, int blk,
                           const float* __restrict__ bf1,
                           const float* __restrict__ bf2,
                           const ushort_t* __restrict__ wf1t,
                           const ushort_t* __restrict__ wf2hi,
                           const ushort_t* __restrict__ wf2lo,
                           ushort_t* __restrict__ tabn) {
    ushort_t (*basis)[72] = (ushort_t (*)[72])smem;                 // 9216 B
    ushort_t (*t1s)[136]  = (ushort_t (*)[136])(smem + 64 * 72 * 2);// 17408 B
    const int tid = threadIdx.x;
    const int g0  = blk * 64;

    for (int i = tid; i < 64 * 64; i += 256) {
        int e = i >> 6, k = i & 63;
        float val = 0.f;
        if (k < NF) {
            float r = (float)(g0 + e) * (5.0f / (float)(NR - 1));
            float d = r - (float)k * DELTA;
            val = __expf(-COEF * d * d);
        }
        basis[e][k] = f2bf(val);
    }
    __syncthreads();

    const int lane = tid & 63;
    const int wv   = tid >> 6;
    const int row  = lane & 15;
    const int quad = lane >> 4;
    const int c0   = (2 * wv) * 16 + row;
    const int c1   = c0 + 16;

    f32x4 acc[2][4];
#pragma unroll
    for (int j = 0; j < 2; j++)
#pragma unroll
        for (int rt = 0; rt < 4; rt++) acc[j][rt] = (f32x4){0.f, 0.f, 0.f, 0.f};

#pragma unroll
    for (int kb = 0; kb < 64; kb += 32) {
        bf16x8 B0 = *(const bf16x8*)&wf1t[c0 * 64 + kb + quad * 8];
        bf16x8 B1 = *(const bf16x8*)&wf1t[c1 * 64 + kb + quad * 8];
#pragma unroll
        for (int rt = 0; rt < 4; rt++) {
            bf16x8 A = *(const bf16x8*)&basis[rt * 16 + row][kb + quad * 8];
            acc[0][rt] = __builtin_amdgcn_mfma_f32_16x16x32_bf16(A, B0, acc[0][rt], 0, 0, 0);
            acc[1][rt] = __builtin_amdgcn_mfma_f32_16x16x32_bf16(A, B1, acc[1][rt], 0, 0, 0);
        }
    }
    {
        float b1v[2] = { bf1[c0], bf1[c1] };
#pragma unroll
        for (int j = 0; j < 2; j++) {
            int c = j ? c1 : c0;
#pragma unroll
            for (int rt = 0; rt < 4; rt++)
#pragma unroll
                for (int rg = 0; rg < 4; rg++) {
                    int e = rt * 16 + quad * 4 + rg;
                    t1s[e][c] = f2bf(ssp(acc[j][rt][rg] + b1v[j]));
                }
        }
    }
    __syncthreads();

#pragma unroll
    for (int j = 0; j < 2; j++)
#pragma unroll
        for (int rt = 0; rt < 4; rt++) acc[j][rt] = (f32x4){0.f, 0.f, 0.f, 0.f};

#pragma unroll
    for (int kb = 0; kb < 128; kb += 32) {
        bf16x8 B0h = *(const bf16x8*)&wf2hi[c0 * CH + kb + quad * 8];
        bf16x8 B0l = *(const bf16x8*)&wf2lo[c0 * CH + kb + quad * 8];
        bf16x8 B1h = *(const bf16x8*)&wf2hi[c1 * CH + kb + quad * 8];
        bf16x8 B1l = *(const bf16x8*)&wf2lo[c1 * CH + kb + quad * 8];
#pragma unroll
        for (int rt = 0; rt < 4; rt++) {
            bf16x8 A = *(const bf16x8*)&t1s[rt * 16 + row][kb + quad * 8];
            acc[0][rt] = __builtin_amdgcn_mfma_f32_16x16x32_bf16(A, B0l, acc[0][rt], 0, 0, 0);
            acc[0][rt] = __builtin_amdgcn_mfma_f32_16x16x32_bf16(A, B0h, acc[0][rt], 0, 0, 0);
            acc[1][rt] = __builtin_amdgcn_mfma_f32_16x16x32_bf16(A, B1l, acc[1][rt], 0, 0, 0);
            acc[1][rt] = __builtin_amdgcn_mfma_f32_16x16x32_bf16(A, B1h, acc[1][rt], 0, 0, 0);
        }
    }
    {
        float b2v[2] = { bf2[c0], bf2[c1] };
#pragma unroll
        for (int j = 0; j < 2; j++) {
            int c = j ? c1 : c0;
#pragma unroll
            for (int rt = 0; rt < 4; rt++)
#pragma unroll
                for (int rg = 0; rg < 4; rg++) {
                    int g = g0 + rt * 16 + quad * 4 + rg;
                    tabn[(size_t)g * CH + c] = f2bf(acc[j][rt][rg] + b2v[j]);
                }
        }
    }
}

__device__ void dense_h_body(char* smem, int blk,
                             const float* __restrict__ X,
                             const ushort_t* __restrict__ Bhi,
                             const ushort_t* __restrict__ Blo,
                             ushort_t* __restrict__ Y) {
    ushort_t (*xs)[136] = (ushort_t (*)[136])smem;
    const int tid  = threadIdx.x;
    const int row0 = blk * 64;

#pragma unroll
    for (int i = 0; i < 8; i++) {
        int idx = tid + i * 256;
        int r   = idx >> 5;
        int c4  = (idx & 31) * 4;
        float4 v = (row0 + r < N_NODES) ? *(const float4*)&X[(size_t)(row0 + r) * CH + c4]
                                        : f4zero();
        ushort4 s;
        s.x = f2bf(v.x); s.y = f2bf(v.y); s.z = f2bf(v.z); s.w = f2bf(v.w);
        *(ushort4*)&xs[r][c4] = s;
    }
    __syncthreads();

    const int lane = tid & 63;
    const int wv   = tid >> 6;
    const int row  = lane & 15;
    const int quad = lane >> 4;
    const int c0   = (2 * wv) * 16 + row;
    const int c1   = c0 + 16;

    f32x4 acc[2][4];
#pragma unroll
    for (int j = 0; j < 2; j++)
#pragma unroll
        for (int rt = 0; rt < 4; rt++) acc[j][rt] = (f32x4){0.f, 0.f, 0.f, 0.f};

#pragma unroll
    for (int kb = 0; kb < 128; kb += 32) {
        bf16x8 B0h = *(const bf16x8*)&Bhi[(size_t)c0 * CH + kb + quad * 8];
        bf16x8 B0l = *(const bf16x8*)&Blo[(size_t)c0 * CH + kb + quad * 8];
        bf16x8 B1h = *(const bf16x8*)&Bhi[(size_t)c1 * CH + kb + quad * 8];
        bf16x8 B1l = *(const bf16x8*)&Blo[(size_t)c1 * CH + kb + quad * 8];
#pragma unroll
        for (int rt = 0; rt < 4; rt++) {
            bf16x8 A = *(const bf16x8*)&xs[rt * 16 + row][kb + quad * 8];
            acc[0][rt] = __builtin_amdgcn_mfma_f32_16x16x32_bf16(A, B0l, acc[0][rt], 0, 0, 0);
            acc[0][rt] = __builtin_amdgcn_mfma_f32_16x16x32_bf16(A, B0h, acc[0][rt], 0, 0, 0);
            acc[1][rt] = __builtin_amdgcn_mfma_f32_16x16x32_bf16(A, B1l, acc[1][rt], 0, 0, 0);
            acc[1][rt] = __builtin_amdgcn_mfma_f32_16x16x32_bf16(A, B1h, acc[1][rt], 0, 0, 0);
        }
    }

#pragma unroll
    for (int j = 0; j < 2; j++) {
        int c = j ? c1 : c0;
#pragma unroll
        for (int rt = 0; rt < 4; rt++)
#pragma unroll
            for (int rg = 0; rg < 4; rg++) {
                int r = row0 + rt * 16 + quad * 4 + rg;
                if (r < N_NODES) Y[(size_t)r * CH + c] = f2bf(acc[j][rt][rg]);
            }
    }
}

__global__ __launch_bounds__(256) void k2_mega(const int* __restrict__ recv,
                                               const int* __restrict__ send,
                                               const float* __restrict__ dist,
                                               int* __restrict__ bcnt,
                                               u64* __restrict__ brec,
                                               const float* __restrict__ bf1,
                                               const float* __restrict__ bf2,
                                               const ushort_t* __restrict__ wf1t,
                                               const ushort_t* __restrict__ wf2hi,
                                               const ushort_t* __restrict__ wf2lo,
                                               ushort_t* __restrict__ tabn,
                                               const float* __restrict__ X,
                                               const ushort_t* __restrict__ wlhi,
                                               const ushort_t* __restrict__ wllo,
                                               ushort_t* __restrict__ h) {
    __shared__ __align__(16) char smem[64 * 72 * 2 + 64 * 136 * 2];   // 26624 B
    const int blk = blockIdx.x;
    if (blk < NBLK_SCAT) {
        scatter_body(smem, blk, recv, send, dist, bcnt, brec);
    } else if (blk < NBLK_SCAT + NBLK_TB) {
        table_body(smem, blk - NBLK_SCAT, bf1, bf2, wf1t, wf2hi, wf2lo, tabn);
    } else {
        dense_h_body(smem, blk - NBLK_SCAT - NBLK_TB, X, wlhi, wllo, h);
    }
}

// ---------------------------------------------------------------------------
// K3: fused sort + gather + output MLP (R10 form + sorted slot pairing).
// Single-pass sort (regs cache 5 recs). Gather: slot g processes perm[g]
// (g-th largest list) and perm[31-g] (g-th smallest) -> near-equal pair sums,
// straggler tail cut without atomics.
// ---------------------------------------------------------------------------
__global__ __launch_bounds__(256) void sort_gather_mlp(const int* __restrict__ bcnt,
                                                       const u64* __restrict__ brec,
                                                       const ushort_t* __restrict__ h,
                                                       const ushort_t* __restrict__ tabn,
                                                       const ushort_t* __restrict__ B1hi,
                                                       const ushort_t* __restrict__ B1lo,
                                                       const float* __restrict__ bm1,
                                                       const ushort_t* __restrict__ B2hi,
                                                       const ushort_t* __restrict__ B2lo,
                                                       const float* __restrict__ bm2,
                                                       float* __restrict__ OUT) {
    __shared__ int shist[BUCKET_NODES];
    __shared__ int sbeg[BUCKET_NODES];
    __shared__ int sexc[BUCKET_NODES];
    __shared__ int perm[BUCKET_NODES];
    __shared__ unsigned sout[CAP];                     // 5120 B
    __shared__ __align__(16) ushort_t at[32][136];     // 8704 B, reused as ts
    const int b = blockIdx.x, tid = threadIdx.x;
    const int nbase = b * BUCKET_NODES;
    const int nn = min(BUCKET_NODES, N_NODES - nbase);
    if (nn <= 0) return;
    const int m = min(bcnt[b], CAP);
    const u64* my = brec + (size_t)b * CAP;

    if (tid < BUCKET_NODES) shist[tid] = 0;
    // zero-pad the A-tile (rows >= nn must be 0 for MFMA)
    for (int i = tid; i < 32 * 17; i += 256) {
        bf16x8 z = (bf16x8){0, 0, 0, 0, 0, 0, 0, 0};
        *(bf16x8*)&at[i / 17][(i % 17) * 8] = z;
    }
    __syncthreads();

    // Single pass: load recs into registers + histogram.
    unsigned pw0 = 0, pw1 = 0, pw2 = 0, pw3 = 0, pw4 = 0;
    int lc0 = -1, lc1 = -1, lc2 = -1, lc3 = -1, lc4 = -1;
    {
        int i;
        i = tid;           if (i < m) { u64 rec = my[i]; lc0 = (int)((rec >> 16) & 0xFFFF) - nbase; pw0 = (unsigned)(rec & 0xFFFF) | ((unsigned)((rec >> 32) & 0x3FFF) << 16); }
        i = tid + 256;     if (i < m) { u64 rec = my[i]; lc1 = (int)((rec >> 16) & 0xFFFF) - nbase; pw1 = (unsigned)(rec & 0xFFFF) | ((unsigned)((rec >> 32) & 0x3FFF) << 16); }
        i = tid + 512;     if (i < m) { u64 rec = my[i]; lc2 = (int)((rec >> 16) & 0xFFFF) - nbase; pw2 = (unsigned)(rec & 0xFFFF) | ((unsigned)((rec >> 32) & 0x3FFF) << 16); }
        i = tid + 768;     if (i < m) { u64 rec = my[i]; lc3 = (int)((rec >> 16) & 0xFFFF) - nbase; pw3 = (unsigned)(rec & 0xFFFF) | ((unsigned)((rec >> 32) & 0x3FFF) << 16); }
        i = tid + 1024;    if (i < m) { u64 rec = my[i]; lc4 = (int)((rec >> 16) & 0xFFFF) - nbase; pw4 = (unsigned)(rec & 0xFFFF) | ((unsigned)((rec >> 32) & 0x3FFF) << 16); }
        if (lc0 >= 0) atomicAdd(&shist[lc0], 1);
        if (lc1 >= 0) atomicAdd(&shist[lc1], 1);
        if (lc2 >= 0) atomicAdd(&shist[lc2], 1);
        if (lc3 >= 0) atomicAdd(&shist[lc3], 1);
        if (lc4 >= 0) atomicAdd(&shist[lc4], 1);
    }
    __syncthreads();
    if (tid == 0) {
        int acc = 0;
#pragma unroll
        for (int l = 0; l < BUCKET_NODES; l++) {
            sexc[l] = acc; sbeg[l] = acc; acc += shist[l];
        }
    }
    __syncthreads();
    // rank pass (sout) + slot-pairing perm, concurrently (disjoint LDS)
    if (tid < BUCKET_NODES) {
        int c = shist[tid];
        int rank = 0;
#pragma unroll
        for (int j = 0; j < BUCKET_NODES; j++) {
            int cj = shist[j];
            rank += (cj > c) || (cj == c && j < tid);
        }
        perm[rank] = tid;
    }
    {
        if (lc0 >= 0) { int rank = atomicAdd(&sexc[lc0], 1); sout[rank] = pw0; }
        if (lc1 >= 0) { int rank = atomicAdd(&sexc[lc1], 1); sout[rank] = pw1; }
        if (lc2 >= 0) { int rank = atomicAdd(&sexc[lc2], 1); sout[rank] = pw2; }
        if (lc3 >= 0) { int rank = atomicAdd(&sexc[lc3], 1); sout[rank] = pw3; }
        if (lc4 >= 0) { int rank = atomicAdd(&sexc[lc4], 1); sout[rank] = pw4; }
    }
    __syncthreads();

    // Phase 2: gather. Slot g -> nodes perm[g] (large) and perm[31-g] (small).
    {
        const int g  = tid >> 4;
        const int c8 = (tid & 15) * 8;
#pragma unroll
        for (int t = 0; t < 2; t++) {
            const int l = perm[t ? (BUCKET_NODES - 1 - g) : g];
            if (l >= nn) continue;
            const int beg = sbeg[l], end = sbeg[l] + shist[l];
            float acc[8];
#pragma unroll
            for (int j = 0; j < 8; j++) acc[j] = 0.f;

            int e = beg;
            for (; e + 8 <= end; e += 8) {
                unsigned v[8];
#pragma unroll
                for (int u = 0; u < 8; u++) v[u] = sout[e + u];
                bf16x8 hu[8], tn[8];
#pragma unroll
                for (int u = 0; u < 8; u++) {
                    int s  = (int)(v[u] & 0xFFFF);
                    int ti = (int)(v[u] >> 16);
                    hu[u] = *(const bf16x8*)&h[(size_t)s * CH + c8];
                    tn[u] = *(const bf16x8*)&tabn[(size_t)ti * CH + c8];
                }
#pragma unroll
                for (int u = 0; u < 8; u++)
#pragma unroll
                    for (int j = 0; j < 8; j++)
                        acc[j] = fmaf(bf2f((ushort_t)hu[u][j]), bf2f((ushort_t)tn[u][j]), acc[j]);
            }
            for (; e + 4 <= end; e += 4) {
                unsigned v[4];
#pragma unroll
                for (int u = 0; u < 4; u++) v[u] = sout[e + u];
                bf16x8 hu[4], tn[4];
#pragma unroll
                for (int u = 0; u < 4; u++) {
                    int s  = (int)(v[u] & 0xFFFF);
                    int ti = (int)(v[u] >> 16);
                    hu[u] = *(const bf16x8*)&h[(size_t)s * CH + c8];
                    tn[u] = *(const bf16x8*)&tabn[(size_t)ti * CH + c8];
                }
#pragma unroll
                for (int u = 0; u < 4; u++)
#pragma unroll
                    for (int j = 0; j < 8; j++)
                        acc[j] = fmaf(bf2f((ushort_t)hu[u][j]), bf2f((ushort_t)tn[u][j]), acc[j]);
            }
            for (; e < end; e++) {
                unsigned v = sout[e];
                int s  = (int)(v & 0xFFFF);
                int ti = (int)(v >> 16);
                bf16x8 hu = *(const bf16x8*)&h[(size_t)s * CH + c8];
                bf16x8 tn = *(const bf16x8*)&tabn[(size_t)ti * CH + c8];
#pragma unroll
                for (int j = 0; j < 8; j++)
                    acc[j] = fmaf(bf2f((ushort_t)hu[j]), bf2f((ushort_t)tn[j]), acc[j]);
            }

            bf16x8 o;
#pragma unroll
            for (int j = 0; j < 8; j++) o[j] = (short)f2bf(acc[j]);
            *(bf16x8*)&at[l][c8] = o;
        }
    }
    __syncthreads();

    // Phase 3: 32-row 2-layer MFMA MLP on the tile.
    const int lane = tid & 63;
    const int wv   = tid >> 6;
    const int row  = lane & 15;
    const int quad = lane >> 4;
    const int c0   = (2 * wv) * 16 + row;
    const int c1   = c0 + 16;

    f32x4 acc[2][2];
#pragma unroll
    for (int j = 0; j < 2; j++)
#pragma unroll
        for (int rt = 0; rt < 2; rt++) acc[j][rt] = (f32x4){0.f, 0.f, 0.f, 0.f};

#pragma unroll
    for (int kb = 0; kb < 128; kb += 32) {
        bf16x8 B0h = *(const bf16x8*)&B1hi[(size_t)c0 * CH + kb + quad * 8];
        bf16x8 B0l = *(const bf16x8*)&B1lo[(size_t)c0 * CH + kb + quad * 8];
        bf16x8 B1h_ = *(const bf16x8*)&B1hi[(size_t)c1 * CH + kb + quad * 8];
        bf16x8 B1l_ = *(const bf16x8*)&B1lo[(size_t)c1 * CH + kb + quad * 8];
#pragma unroll
        for (int rt = 0; rt < 2; rt++) {
            bf16x8 A = *(const bf16x8*)&at[rt * 16 + row][kb + quad * 8];
            acc[0][rt] = __builtin_amdgcn_mfma_f32_16x16x32_bf16(A, B0l, acc[0][rt], 0, 0, 0);
            acc[0][rt] = __builtin_amdgcn_mfma_f32_16x16x32_bf16(A, B0h, acc[0][rt], 0, 0, 0);
            acc[1][rt] = __builtin_amdgcn_mfma_f32_16x16x32_bf16(A, B1l_, acc[1][rt], 0, 0, 0);
            acc[1][rt] = __builtin_amdgcn_mfma_f32_16x16x32_bf16(A, B1h_, acc[1][rt], 0, 0, 0);
        }
    }
    __syncthreads();   // GEMM1 reads complete before overwrite
    {
        float bv[2] = { bm1[c0], bm1[c1] };
#pragma unroll
        for (int j = 0; j < 2; j++) {
            int c = j ? c1 : c0;
#pragma unroll
            for (int rt = 0; rt < 2; rt++)
#pragma unroll
                for (int rg = 0; rg < 4; rg++)
                    at[rt * 16 + quad * 4 + rg][c] = f2bf(ssp(acc[j][rt][rg] + bv[j]));
        }
    }
    __syncthreads();

#pragma unroll
    for (int j = 0; j < 2; j++)
#pragma unroll
        for (int rt = 0; rt < 2; rt++) acc[j][rt] = (f32x4){0.f, 0.f, 0.f, 0.f};

#pragma unroll
    for (int kb = 0; kb < 128; kb += 32) {
        bf16x8 B0h = *(const bf16x8*)&B2hi[(size_t)c0 * CH + kb + quad * 8];
        bf16x8 B0l = *(const bf16x8*)&B2lo[(size_t)c0 * CH + kb + quad * 8];
        bf16x8 B1h_ = *(const bf16x8*)&B2hi[(size_t)c1 * CH + kb + quad * 8];
        bf16x8 B1l_ = *(const bf16x8*)&B2lo[(size_t)c1 * CH + kb + quad * 8];
#pragma unroll
        for (int rt = 0; rt < 2; rt++) {
            bf16x8 A = *(const bf16x8*)&at[rt * 16 + row][kb + quad * 8];
            acc[0][rt] = __builtin_amdgcn_mfma_f32_16x16x32_bf16(A, B0l, acc[0][rt], 0, 0, 0);
            acc[0][rt] = __builtin_amdgcn_mfma_f32_16x16x32_bf16(A, B0h, acc[0][rt], 0, 0, 0);
            acc[1][rt] = __builtin_amdgcn_mfma_f32_16x16x32_bf16(A, B1l_, acc[1][rt], 0, 0, 0);
            acc[1][rt] = __builtin_amdgcn_mfma_f32_16x16x32_bf16(A, B1h_, acc[1][rt], 0, 0, 0);
        }
    }
    {
        float bv[2] = { bm2[c0], bm2[c1] };
#pragma unroll
        for (int j = 0; j < 2; j++) {
            int c = j ? c1 : c0;
#pragma unroll
            for (int rt = 0; rt < 2; rt++)
#pragma unroll
                for (int rg = 0; rg < 4; rg++) {
                    int r = rt * 16 + quad * 4 + rg;
                    if (r < nn) OUT[(size_t)(nbase + r) * CH + c] = acc[j][rt][rg] + bv[j];
                }
        }
    }
}

// ---------------------------------------------------------------------------
extern "C" void kernel_launch(void* const* d_in, const int* in_sizes, int n_in,
                              void* d_out, int out_size, void* d_ws, size_t ws_size,
                              hipStream_t stream) {
    const float* features = (const float*)d_in[0];
    const float* dist     = (const float*)d_in[1];
    const float* W_lin    = (const float*)d_in[2];
    const float* Wf1      = (const float*)d_in[3];
    const float* bf1      = (const float*)d_in[4];
    const float* Wf2      = (const float*)d_in[5];
    const float* bf2      = (const float*)d_in[6];
    const float* Wm1      = (const float*)d_in[7];
    const float* bm1      = (const float*)d_in[8];
    const float* Wm2      = (const float*)d_in[9];
    const float* bm2      = (const float*)d_in[10];
    const int* senders    = (const int*)d_in[11];
    const int* receivers  = (const int*)d_in[12];
    float* out = (float*)d_out;

    // workspace (~31 MB)
    u64* brec       = (u64*)d_ws;                            // [NB*CAP] 16.0 MB
    ushort_t* h     = (ushort_t*)(brec + (size_t)NB * CAP);  // [N,128] 12.8 MB
    ushort_t* tabn  = h + (size_t)N_NODES * CH;              // [NR,128] 2 MB
    int* bcnt       = (int*)(tabn + (size_t)NR * CH);        // [NB] 6.3 KB
    ushort_t* wlhi  = (ushort_t*)(bcnt + NB);
    ushort_t* wllo  = wlhi  + CH * CH;
    ushort_t* wm1hi = wllo  + CH * CH;
    ushort_t* wm1lo = wm1hi + CH * CH;
    ushort_t* wm2hi = wm1lo + CH * CH;
    ushort_t* wm2lo = wm2hi + CH * CH;
    ushort_t* wf1t  = wm2lo + CH * CH;                       // [128*64]
    ushort_t* wf2hi = wf1t  + CH * 64;
    ushort_t* wf2lo = wf2hi + CH * CH;

    // K1: weight prep + zero bcnt
    k1_prep<<<65, 256, 0, stream>>>(W_lin, Wm1, Wm2, Wf1, Wf2,
                                    wlhi, wllo, wm1hi, wm1lo, wm2hi, wm2lo,
                                    wf1t, wf2hi, wf2lo, bcnt);

    // K2: [bucket_scatter | table_mfma | dense_h]
    k2_mega<<<NBLK_SCAT + NBLK_TB + NBLK_DH, 256, 0, stream>>>(
        receivers, senders, dist, bcnt, brec,
        bf1, bf2, wf1t, wf2hi, wf2lo, tabn,
        features, wlhi, wllo, h);

    // K3: fused sort + gather + output MLP -> d_out (1563 blocks)
    sort_gather_mlp<<<NB, 256, 0, stream>>>(bcnt, brec, h, tabn,
                                            wm1hi, wm1lo, bm1,
                                            wm2hi, wm2lo, bm2, out);
}